// Round 10
// baseline (687.489 us; speedup 1.0000x reference)
//
#include <hip/hip_runtime.h>
#include <hip/hip_bf16.h>
#include <cstdint>

// ---------------------------------------------------------------------------
// EncoderLayer fused pipeline for MI355X (gfx950)
// B=4 S=2048 D=1024 H=16 DK=64 DFF=4096   M = B*S = 8192
// ---------------------------------------------------------------------------

typedef __bf16 bf16x8 __attribute__((ext_vector_type(8)));
typedef float  f32x4  __attribute__((ext_vector_type(4)));

__device__ __forceinline__ uint16_t f2bf_bits(float f) {
    __hip_bfloat16 h = __float2bfloat16(f);
    return __builtin_bit_cast(uint16_t, h);
}

// async global->LDS, 16B per lane; lds base must be wave-uniform
#define GLOAD16(ldsb, gp) __builtin_amdgcn_global_load_lds( \
    (const __attribute__((address_space(1))) void*)(gp),    \
    (__attribute__((address_space(3))) void*)(ldsb), 16, 0, 0)

// Q pre-scale: DK^-0.5 * log2(e); softmax then runs in exp2 domain.
#define QSCALE_LOG2E 0.18033688011112f

// ---------------------------------------------------------------------------
// cast f32 -> bf16 (vectorized)
__global__ __launch_bounds__(256) void cast_bf16_kernel(
    const float* __restrict__ in, __hip_bfloat16* __restrict__ out, size_t n4)
{
    size_t i = (size_t)blockIdx.x * blockDim.x + threadIdx.x;
    if (i >= n4) return;
    float4 v = ((const float4*)in)[i];
    ushort4 o;
    o.x = f2bf_bits(v.x); o.y = f2bf_bits(v.y);
    o.z = f2bf_bits(v.z); o.w = f2bf_bits(v.w);
    ((ushort4*)out)[i] = o;
}

// ---------------------------------------------------------------------------
// transpose + cast: in [K][N] f32 -> out [N][K] bf16. grid (N/32, K/32), block (32,8)
__global__ __launch_bounds__(256) void transpose_cast_kernel(
    const float* __restrict__ in, __hip_bfloat16* __restrict__ out, int K, int N)
{
    __shared__ float t[32][33];
    int n0 = blockIdx.x * 32, k0 = blockIdx.y * 32;
    int tx = threadIdx.x, ty = threadIdx.y;
#pragma unroll
    for (int i = 0; i < 4; ++i)
        t[ty + i * 8][tx] = in[(size_t)(k0 + ty + i * 8) * N + n0 + tx];
    __syncthreads();
#pragma unroll
    for (int i = 0; i < 4; ++i)
        out[(size_t)(n0 + ty + i * 8) * K + k0 + tx] = __float2bfloat16(t[tx][ty + i * 8]);
}

// ---------------------------------------------------------------------------
// gate = sigmoid(x @ w_g + b_g)   x:[8192][1024] f32, w_g:[1024][16], gate:[8192][16]
__global__ __launch_bounds__(256) void gate_kernel(
    const float* __restrict__ x, const float* __restrict__ wg,
    const float* __restrict__ bg, float* __restrict__ gate)
{
    int tid = threadIdx.x, lane = tid & 63, wid = tid >> 6;
    int row = blockIdx.x * 4 + wid;
    const float* xr = x + (size_t)row * 1024;
    float acc[16];
#pragma unroll
    for (int hh = 0; hh < 16; ++hh) acc[hh] = 0.0f;
    for (int k = lane; k < 1024; k += 64) {
        float xv = xr[k];
        const float* wr = wg + (size_t)k * 16;
#pragma unroll
        for (int hh = 0; hh < 16; ++hh) acc[hh] = fmaf(xv, wr[hh], acc[hh]);
    }
#pragma unroll
    for (int hh = 0; hh < 16; ++hh) {
#pragma unroll
        for (int d = 1; d < 64; d <<= 1) acc[hh] += __shfl_xor(acc[hh], d);
    }
    if (lane < 16) {
        float v = 0.0f;
#pragma unroll
        for (int hh = 0; hh < 16; ++hh)
            if (lane == hh) v = acc[hh] + bg[hh];
        gate[(size_t)row * 16 + lane] = 1.0f / (1.0f + __expf(-v));
    }
}

// ---------------------------------------------------------------------------
// LayerNorm(a + b) -> outf (f32) and optionally outb (bf16). One block per row.
__global__ __launch_bounds__(256) void ln_kernel(
    const float* __restrict__ A, const float* __restrict__ Bx,
    const float* __restrict__ g, const float* __restrict__ beta,
    float* __restrict__ outf, __hip_bfloat16* __restrict__ outb)
{
    int row = blockIdx.x, tid = threadIdx.x;
    const float4* a4 = (const float4*)(A  + (size_t)row * 1024);
    const float4* b4 = (const float4*)(Bx + (size_t)row * 1024);
    float4 va = a4[tid], vb = b4[tid];
    float x0 = va.x + vb.x, x1 = va.y + vb.y, x2 = va.z + vb.z, x3 = va.w + vb.w;
    float s  = x0 + x1 + x2 + x3;
    float sq = x0 * x0 + x1 * x1 + x2 * x2 + x3 * x3;
#pragma unroll
    for (int d = 1; d < 64; d <<= 1) { s += __shfl_xor(s, d); sq += __shfl_xor(sq, d); }
    __shared__ float ss[4], ssq[4];
    int wid = tid >> 6, lane = tid & 63;
    if (lane == 0) { ss[wid] = s; ssq[wid] = sq; }
    __syncthreads();
    s  = ss[0] + ss[1] + ss[2] + ss[3];
    sq = ssq[0] + ssq[1] + ssq[2] + ssq[3];
    float mean = s * (1.0f / 1024.0f);
    float var  = sq * (1.0f / 1024.0f) - mean * mean;
    float rstd = rsqrtf(var + 1e-5f);
    float4 gv = ((const float4*)g)[tid], bv = ((const float4*)beta)[tid];
    float y0 = (x0 - mean) * rstd * gv.x + bv.x;
    float y1 = (x1 - mean) * rstd * gv.y + bv.y;
    float y2 = (x2 - mean) * rstd * gv.z + bv.z;
    float y3 = (x3 - mean) * rstd * gv.w + bv.w;
    float4 o; o.x = y0; o.y = y1; o.z = y2; o.w = y3;
    ((float4*)(outf + (size_t)row * 1024))[tid] = o;
    if (outb) {
        ushort4 ob;
        ob.x = f2bf_bits(y0); ob.y = f2bf_bits(y1);
        ob.z = f2bf_bits(y2); ob.w = f2bf_bits(y3);
        ((ushort4*)(outb + (size_t)row * 1024))[tid] = ob;
    }
}

// ---------------------------------------------------------------------------
// GEMM 128x128 (m97 structure): C = A[M][K] @ BT[N][K]^T + bias.
//  EPI 0: f32 [M][N]
//  EPI 1: q  bf16 [B,H,S,DK], scaled by DK^-0.5*log2e (exp2-domain softmax)
//  EPI 2: k  bf16 [B,H,S,DK]
//  EPI 3: v  bf16 [B,H,DK,S]  (transposed)
template<int EPI>
__global__ __launch_bounds__(256, 2) void gemm128(
    const __hip_bfloat16* __restrict__ A,
    const __hip_bfloat16* __restrict__ BT,
    const float* __restrict__ bias,
    void* __restrict__ Cout, int M, int N, int K)
{
    __shared__ __align__(16) __hip_bfloat16 As[128 * 64];
    __shared__ __align__(16) __hip_bfloat16 Bs[128 * 64];
    const int tid = threadIdx.x, lane = tid & 63, wid = tid >> 6;
    const int bx = blockIdx.x, by = blockIdx.y;
    const int wr = wid >> 1, wc = wid & 1;

    f32x4 acc[4][4];
#pragma unroll
    for (int i = 0; i < 4; ++i)
#pragma unroll
        for (int j = 0; j < 4; ++j) acc[i][j] = (f32x4){0.f, 0.f, 0.f, 0.f};

    const char* Abase = (const char*)A  + (size_t)(by * 128) * K * 2;
    const char* Bbase = (const char*)BT + (size_t)(bx * 128) * K * 2;
    char* AsB = (char*)As; char* BsB = (char*)Bs;
    const int laneRow = lane >> 3;            // 0..7
    const int laneCol = (lane & 7) * 16;      // byte col in 128B row

    for (int ks = 0; ks < K; ks += 64) {
#pragma unroll
        for (int j = 0; j < 4; ++j) {
            int r = j * 32 + wid * 8 + laneRow;
            size_t goff = (size_t)r * K * 2 + (size_t)ks * 2 + laneCol;
            GLOAD16(AsB + j * 4096 + wid * 1024, Abase + goff);
            GLOAD16(BsB + j * 4096 + wid * 1024, Bbase + goff);
        }
        __syncthreads();
#pragma unroll
        for (int kk = 0; kk < 2; ++kk) {
            const int kob = (kk * 32 + (lane >> 4) * 8) * 2;  // byte offset in k
            bf16x8 a[4], b[4];
#pragma unroll
            for (int mt = 0; mt < 4; ++mt)
                a[mt] = *(const bf16x8*)(AsB + (wr * 64 + mt * 16 + (lane & 15)) * 128 + kob);
#pragma unroll
            for (int nt = 0; nt < 4; ++nt)
                b[nt] = *(const bf16x8*)(BsB + (wc * 64 + nt * 16 + (lane & 15)) * 128 + kob);
#pragma unroll
            for (int mt = 0; mt < 4; ++mt)
#pragma unroll
                for (int nt = 0; nt < 4; ++nt)
                    acc[mt][nt] = __builtin_amdgcn_mfma_f32_16x16x32_bf16(
                        a[mt], b[nt], acc[mt][nt], 0, 0, 0);
        }
        __syncthreads();
    }

    const int m0 = by * 128 + wr * 64;
    const int n0 = bx * 128 + wc * 64;
#pragma unroll
    for (int mt = 0; mt < 4; ++mt) {
#pragma unroll
        for (int nt = 0; nt < 4; ++nt) {
            int n = n0 + nt * 16 + (lane & 15);
            float bv = bias[n];
#pragma unroll
            for (int j = 0; j < 4; ++j) {
                int m = m0 + mt * 16 + (lane >> 4) * 4 + j;
                float v = acc[mt][nt][j] + bv;
                if constexpr (EPI == 0) {
                    ((float*)Cout)[(size_t)m * N + n] = v;
                } else if constexpr (EPI == 1) {
                    int b = m >> 11, s = m & 2047, h = n >> 6, dk = n & 63;
                    ((__hip_bfloat16*)Cout)[((((size_t)b * 16 + h) * 2048 + s) << 6) + dk] =
                        __float2bfloat16(v * QSCALE_LOG2E);
                } else if constexpr (EPI == 2) {
                    int b = m >> 11, s = m & 2047, h = n >> 6, dk = n & 63;
                    ((__hip_bfloat16*)Cout)[((((size_t)b * 16 + h) * 2048 + s) << 6) + dk] =
                        __float2bfloat16(v);
                } else if constexpr (EPI == 3) {
                    int b = m >> 11, s = m & 2047, h = n >> 6, dk = n & 63;
                    ((__hip_bfloat16*)Cout)[(((size_t)b * 16 + h) * 64 + dk) * 2048 + s] =
                        __float2bfloat16(v);
                }
            }
        }
    }
}

// ---------------------------------------------------------------------------
// GEMM 256x256, 8-wave (2Mx4N), BK=64, 4-phase/K-tile schedule with dbuf LDS,
// counted vmcnt (T4), XOR-swizzled LDS both-sides (T2), setprio (T5).
// EPI 6: gelu -> bf16 [M][N]   (only FF1 uses this kernel now)
template<int EPI>
__global__ __launch_bounds__(512, 2) void gemm256(
    const __hip_bfloat16* __restrict__ A,
    const __hip_bfloat16* __restrict__ BT,
    const float* __restrict__ bias0,
    __hip_bfloat16* __restrict__ out0,
    int M, int N, int K)
{
    __shared__ __align__(16) char lds_[131072];   // 2 x (A 32KB + B 32KB)
    const int tid = threadIdx.x;
    const int lane = tid & 63;
    const int l15 = lane & 15;
    const int wid = tid >> 6;
    const int wm = wid >> 2, wn = wid & 3;

    // XCD-aware 1D swizzle (grid % 8 == 0 for all our launches)
    const int NBX = N >> 8;
    const int cpx = ((M >> 8) * NBX) >> 3;
    const int nl = ((int)blockIdx.x & 7) * cpx + ((int)blockIdx.x >> 3);
    const int by = nl / NBX, bx = nl % NBX;

    const char* Abase = (const char*)A  + (size_t)(by * 256) * K * 2;
    const char* Bbase = (const char*)BT + (size_t)(bx * 256) * K * 2;

    // staging lane geometry: chunk = 64 rows x 128B; lane -> row tid>>3, slot tid&7
    const int srow = tid >> 3;
    const int ssw  = ((tid & 7) ^ (srow & 7)) * 16;   // pre-swizzled source slot

    f32x4 acc[8][4];
#pragma unroll
    for (int i = 0; i < 8; ++i)
#pragma unroll
        for (int j = 0; j < 4; ++j) acc[i][j] = (f32x4){0.f, 0.f, 0.f, 0.f};

    // stage chunk c of A/B K-block ks into dbuf d
    auto stageA = [&](int d, int c, int ks) {
        const char* src = Abase + ((size_t)(c * 64 + srow) * K + ks) * 2 + ssw;
        GLOAD16(lds_ + d * 65536 + c * 8192 + wid * 1024, src);
    };
    auto stageB = [&](int d, int c, int ks) {
        const char* src = Bbase + ((size_t)(c * 64 + srow) * K + ks) * 2 + ssw;
        GLOAD16(lds_ + d * 65536 + 32768 + c * 8192 + wid * 1024, src);
    };

    const int NT = K >> 6;
    // prologue: stage tile 0 fully, drain, barrier
    stageB(0, 0, 0); stageB(0, 1, 0); stageB(0, 2, 0); stageB(0, 3, 0);
    stageA(0, 0, 0); stageA(0, 2, 0); stageA(0, 1, 0); stageA(0, 3, 0);
    asm volatile("s_waitcnt vmcnt(0)" ::: "memory");
    __builtin_amdgcn_s_barrier();

    for (int t = 0; t < NT; ++t) {
        const int cur = t & 1, nxt = cur ^ 1;
        const int ksn = (t + 1) << 6;
        const bool st = (t + 1 < NT);
        const char* ldsA = lds_ + cur * 65536;
        const char* ldsB = ldsA + 32768;

        bf16x8 bfr[4][2];
#pragma unroll
        for (int p = 0; p < 4; ++p) {
            // --- ds_read this phase's fragments (data guaranteed by prior vmcnt+barrier)
            if (p == 0) {
#pragma unroll
                for (int nf = 0; nf < 4; ++nf) {
                    const int br = wn * 64 + nf * 16 + l15;
#pragma unroll
                    for (int kk = 0; kk < 2; ++kk) {
                        const int kb = kk * 64 + (lane >> 4) * 16;
                        bfr[nf][kk] = *(const bf16x8*)(ldsB + (br >> 6) * 8192 +
                            (br & 63) * 128 + (kb ^ ((br & 7) << 4)));
                    }
                }
            }
            bf16x8 afr[2][2];
#pragma unroll
            for (int mi = 0; mi < 2; ++mi) {
                const int ar = wm * 128 + (2 * p + mi) * 16 + l15;
#pragma unroll
                for (int kk = 0; kk < 2; ++kk) {
                    const int kb = kk * 64 + (lane >> 4) * 16;
                    afr[mi][kk] = *(const bf16x8*)(ldsA + (ar >> 6) * 8192 +
                        (ar & 63) * 128 + (kb ^ ((ar & 7) << 4)));
                }
            }
            // --- issue next-tile staging (one chunk pair per phase)
            if (st) {
                if      (p == 0) { stageB(nxt, 0, ksn); stageB(nxt, 1, ksn); }
                else if (p == 1) { stageB(nxt, 2, ksn); stageB(nxt, 3, ksn); }
                else if (p == 2) { stageA(nxt, 0, ksn); stageA(nxt, 2, ksn); }
                else             { stageA(nxt, 1, ksn); stageA(nxt, 3, ksn); }
            }
            __builtin_amdgcn_s_barrier();
            // --- MFMA cluster (compiler inserts lgkm waits for afr/bfr)
            __builtin_amdgcn_s_setprio(1);
#pragma unroll
            for (int mi = 0; mi < 2; ++mi)
#pragma unroll
                for (int nf = 0; nf < 4; ++nf)
#pragma unroll
                    for (int kk = 0; kk < 2; ++kk)
                        acc[2 * p + mi][nf] = __builtin_amdgcn_mfma_f32_16x16x32_bf16(
                            afr[mi][kk], bfr[nf][kk], acc[2 * p + mi][nf], 0, 0, 0);
            __builtin_amdgcn_s_setprio(0);
            // --- counted vmcnt: never drain to 0 in steady state
            if (p == 1) asm volatile("s_waitcnt vmcnt(4)" ::: "memory");
            if (p == 3) asm volatile("s_waitcnt vmcnt(2)" ::: "memory");
            __builtin_amdgcn_s_barrier();
        }
    }

    // ---- epilogue (EPI 6: gelu -> bf16 [M][N])
    const int nbase = bx * 256 + wn * 64;
    const int mbase = by * 256 + wm * 128;
#pragma unroll
    for (int mf = 0; mf < 8; ++mf) {
#pragma unroll
        for (int nf = 0; nf < 4; ++nf) {
            const int n = nbase + nf * 16 + l15;
            const float bv = bias0[n];
#pragma unroll
            for (int j = 0; j < 4; ++j) {
                const int m = mbase + mf * 16 + (lane >> 4) * 4 + j;
                const float v = acc[mf][nf][j] + bv;
                const float ge = 0.5f * v * (1.0f + erff(v * 0.70710678118654752f));
                out0[(size_t)m * N + n] = __float2bfloat16(ge);
            }
        }
    }
}

// ---------------------------------------------------------------------------
// Flash attention. Q:[BH][S][64] bf16 (pre-scaled by DK^-0.5*log2e), K, Vt.
// Softmax in exp2 domain (v_exp_f32 is natively 2^x; saves the ln2 mul/elem).
// Defer-max (THR=11 bits ~ 7.6 nats), l-reduce deferred to epilogue.
__global__ __launch_bounds__(256, 2) void attn_kernel(
    const __hip_bfloat16* __restrict__ Q,
    const __hip_bfloat16* __restrict__ Kg,
    const __hip_bfloat16* __restrict__ Vt,
    const float* __restrict__ gate,
    const int* __restrict__ mask,
    __hip_bfloat16* __restrict__ ctx)
{
    __shared__ __align__(16) __hip_bfloat16 Ks[64 * 64];
    __shared__ __align__(16) __hip_bfloat16 Vs[64 * 64];
    __shared__ __align__(16) __hip_bfloat16 Ps[4][16 * 64];
    const int tid = threadIdx.x, lane = tid & 63, wid = tid >> 6;

    // XCD swizzle: 2048 blocks, 8 XCDs, 256 blocks/XCD. nwg%8==0 -> bijective.
    int lin = blockIdx.x;
    int nl  = (lin & 7) * 256 + (lin >> 3);
    const int bh = nl >> 5, qt = nl & 31;
    const int b = bh >> 4, h = bh & 15;
    const int q0 = qt * 64 + wid * 16;

    // Q fragments in registers (A-operand: row = lane&15, k contiguous)
    bf16x8 aq[2];
    const __hip_bfloat16* Qbase = Q + ((size_t)bh * 2048 + q0) * 64;
#pragma unroll
    for (int kk = 0; kk < 2; ++kk)
        aq[kk] = *(const bf16x8*)(Qbase + (lane & 15) * 64 + kk * 32 + (lane >> 4) * 8);

    f32x4 octx[4];
#pragma unroll
    for (int dt = 0; dt < 4; ++dt) octx[dt] = (f32x4){0.f, 0.f, 0.f, 0.f};
    float l_part[4] = {0.f, 0.f, 0.f, 0.f};
    float m_cur = 0.0f;                 // wave-uniform deferred max (log2 units)

    const char* Kbase = (const char*)(Kg + (size_t)bh * 2048 * 64);
    const char* Vbase = (const char*)(Vt + (size_t)bh * 64 * 2048);
    char* KsB = (char*)Ks; char* VsB = (char*)Vs;
    char* PsB = (char*)&Ps[wid][0];

    const int srow = (lane >> 3);             // 0..7 row within wave's slab
    const int schunk = lane & 7;              // 16B chunk within 128B row

    for (int kv0 = 0; kv0 < 2048; kv0 += 64) {
#pragma unroll
        for (int j = 0; j < 2; ++j) {
            int off = j * 4096 + wid * 1024;
            int row = j * 32 + wid * 8 + srow;                 // kv row / dk row
            int sc  = (schunk ^ (row & 7)) * 16;               // pre-swizzled source chunk
            GLOAD16(KsB + off, Kbase + (size_t)(kv0 + row) * 128 + sc);
            GLOAD16(VsB + off, Vbase + (size_t)row * 4096 + (size_t)kv0 * 2 + sc);
        }
        // hoist mask loads (used after QK^T; latency hides under staging+MFMA)
        float madd[4];
#pragma unroll
        for (int ct = 0; ct < 4; ++ct) {
            int kvi = kv0 + ct * 16 + (lane & 15);
            madd[ct] = (mask[b * 2048 + kvi] == 0) ? -1e9f : 0.0f;
        }
        __syncthreads();

        // QK^T: scores[q 16][kv 64] per wave (log2 domain)
        f32x4 sfr[4];
#pragma unroll
        for (int ct = 0; ct < 4; ++ct) sfr[ct] = (f32x4){0.f, 0.f, 0.f, 0.f};
        __builtin_amdgcn_s_setprio(1);
#pragma unroll
        for (int kk = 0; kk < 2; ++kk) {
            const int kob = (kk * 32 + (lane >> 4) * 8) * 2;
#pragma unroll
            for (int ct = 0; ct < 4; ++ct) {
                int krow = ct * 16 + (lane & 15);
                bf16x8 bk = *(const bf16x8*)(KsB + ((krow * 128 + kob) ^ ((krow & 7) << 4)));
                sfr[ct] = __builtin_amdgcn_mfma_f32_16x16x32_bf16(aq[kk], bk, sfr[ct], 0, 0, 0);
            }
        }
        __builtin_amdgcn_s_setprio(0);
#pragma unroll
        for (int ct = 0; ct < 4; ++ct) {
#pragma unroll
            for (int r = 0; r < 4; ++r) sfr[ct][r] += madd[ct];
        }

        // lane-local max of this lane's 16 score elements (no cross-lane)
        float mlane = sfr[0][0];
#pragma unroll
        for (int ct = 0; ct < 4; ++ct)
#pragma unroll
            for (int r = 0; r < 4; ++r) mlane = fmaxf(mlane, sfr[ct][r]);

        if (kv0 == 0) {
            // one-time init: m_cur = wave max
            float wm = mlane;
#pragma unroll
            for (int d = 1; d < 64; d <<= 1) wm = fmaxf(wm, __shfl_xor(wm, d));
            m_cur = wm;
        } else if (!__all(mlane <= m_cur + 11.0f)) {
            // rare slow path: raise m_cur, rescale state (uniform factor)
            float wm = mlane;
#pragma unroll
            for (int d = 1; d < 64; d <<= 1) wm = fmaxf(wm, __shfl_xor(wm, d));
            wm = fmaxf(wm, m_cur);
            float c = exp2f(m_cur - wm);
            m_cur = wm;
#pragma unroll
            for (int dt = 0; dt < 4; ++dt)
#pragma unroll
                for (int r = 0; r < 4; ++r) octx[dt][r] *= c;
#pragma unroll
            for (int r = 0; r < 4; ++r) l_part[r] *= c;
        }

        // P = 2^(s - m_cur) (bounded by 2^11), accumulate per-lane l, store P
#pragma unroll
        for (int ct = 0; ct < 4; ++ct) {
#pragma unroll
            for (int r = 0; r < 4; ++r) {
                float p = exp2f(sfr[ct][r] - m_cur);
                l_part[r] += p;
                int qr = (lane >> 4) * 4 + r;
                int byteoff = (qr * 128 + (ct * 16 + (lane & 15)) * 2) ^ ((qr & 7) << 4);
                *(__hip_bfloat16*)(PsB + byteoff) = __float2bfloat16(p);
            }
        }
        // PV: ctx[q 16][dk 64] += P @ V
        __builtin_amdgcn_s_setprio(1);
#pragma unroll
        for (int kk = 0; kk < 2; ++kk) {
            const int kb = kk * 32 + (lane >> 4) * 8;
            int pbyte = ((lane & 15) * 128 + kb * 2) ^ (((lane & 15) & 7) << 4);
            bf16x8 ap = *(const bf16x8*)(PsB + pbyte);
#pragma unroll
            for (int dt = 0; dt < 4; ++dt) {
                int vrow = dt * 16 + (lane & 15);
                bf16x8 bvv = *(const bf16x8*)(VsB + ((vrow * 128 + kb * 2) ^ ((vrow & 7) << 4)));
                octx[dt] = __builtin_amdgcn_mfma_f32_16x16x32_bf16(ap, bvv, octx[dt], 0, 0, 0);
            }
        }
        __builtin_amdgcn_s_setprio(0);
        __syncthreads();
    }

    // deferred cross-lane l reduction: sum over the 16 lanes sharing lane>>4
#pragma unroll
    for (int r = 0; r < 4; ++r) {
        float s = l_part[r];
        s += __shfl_xor(s, 1); s += __shfl_xor(s, 2);
        s += __shfl_xor(s, 4); s += __shfl_xor(s, 8);
        l_part[r] = s;
    }

    // epilogue: ctx * gate / l  -> bf16 [M][1024]
#pragma unroll
    for (int r = 0; r < 4; ++r) {
        int qg = q0 + (lane >> 4) * 4 + r;
        size_t rowm = (size_t)b * 2048 + qg;
        float gv = gate[rowm * 16 + h];
        float inv = gv / l_part[r];
#pragma unroll
        for (int dt = 0; dt < 4; ++dt)
            ctx[rowm * 1024 + h * 64 + dt * 16 + (lane & 15)] =
                __float2bfloat16(octx[dt][r] * inv);
    }
}

// ---------------------------------------------------------------------------
extern "C" void kernel_launch(void* const* d_in, const int* in_sizes, int n_in,
                              void* d_out, int out_size, void* d_ws, size_t ws_size,
                              hipStream_t stream)
{
    const float* x    = (const float*)d_in[0];
    const float* w_q  = (const float*)d_in[1];
    const float* b_q  = (const float*)d_in[2];
    const float* w_k  = (const float*)d_in[3];
    const float* b_k  = (const float*)d_in[4];
    const float* w_v  = (const float*)d_in[5];
    const float* b_v  = (const float*)d_in[6];
    const float* w_o  = (const float*)d_in[7];
    const float* b_o  = (const float*)d_in[8];
    const float* w_g  = (const float*)d_in[9];
    const float* b_g  = (const float*)d_in[10];
    const float* w1   = (const float*)d_in[11];
    const float* b1   = (const float*)d_in[12];
    const float* w2   = (const float*)d_in[13];
    const float* b2   = (const float*)d_in[14];
    const float* g1   = (const float*)d_in[15];
    const float* be1  = (const float*)d_in[16];
    const float* g2   = (const float*)d_in[17];
    const float* be2  = (const float*)d_in[18];
    const int*   mask = (const int*)d_in[19];

    char* ws = (char*)d_ws;
    size_t off = 0;
    auto alloc = [&](size_t bytes) -> char* {
        char* p = ws + off; off += (bytes + 255) & ~(size_t)255; return p;
    };

    // Region A: xb | q | k | v  (later reused as FF hidden buffer, 64MB)
    char* regionA = alloc(67108864);
    __hip_bfloat16* xb   = (__hip_bfloat16*)regionA;
    __hip_bfloat16* qb   = (__hip_bfloat16*)(regionA + 16777216);
    __hip_bfloat16* kb   = (__hip_bfloat16*)(regionA + 33554432);
    __hip_bfloat16* vb   = (__hip_bfloat16*)(regionA + 50331648);
    __hip_bfloat16* hbuf = (__hip_bfloat16*)regionA;   // alias (FF1 out / FF2 in)

    __hip_bfloat16* wqT = (__hip_bfloat16*)alloc(2097152);
    __hip_bfloat16* wkT = (__hip_bfloat16*)alloc(2097152);
    __hip_bfloat16* wvT = (__hip_bfloat16*)alloc(2097152);
    __hip_bfloat16* woT = (__hip_bfloat16*)alloc(2097152);
    __hip_bfloat16* w1T = (__hip_bfloat16*)alloc(8388608);
    __hip_bfloat16* w2T = (__hip_bfloat16*)alloc(8388608);
    float* gate       = (float*)alloc(524288);
    __hip_bfloat16* ctx = (__hip_bfloat16*)alloc(16777216);
    float* attn_out   = (float*)alloc(33554432);   // reused as ff2 out
    float* x1f        = (float*)alloc(33554432);
    __hip_bfloat16* x1b = (__hip_bfloat16*)alloc(16777216);

    dim3 tb(32, 8);
    cast_bf16_kernel<<<8192, 256, 0, stream>>>(x, xb, 2097152);
    transpose_cast_kernel<<<dim3(32, 32),  tb, 0, stream>>>(w_q, wqT, 1024, 1024);
    transpose_cast_kernel<<<dim3(32, 32),  tb, 0, stream>>>(w_k, wkT, 1024, 1024);
    transpose_cast_kernel<<<dim3(32, 32),  tb, 0, stream>>>(w_v, wvT, 1024, 1024);
    transpose_cast_kernel<<<dim3(32, 32),  tb, 0, stream>>>(w_o, woT, 1024, 1024);
    transpose_cast_kernel<<<dim3(128, 32), tb, 0, stream>>>(w1, w1T, 1024, 4096);
    transpose_cast_kernel<<<dim3(32, 128), tb, 0, stream>>>(w2, w2T, 4096, 1024);
    gate_kernel<<<2048, 256, 0, stream>>>(x, w_g, b_g, gate);

    // QKV on gemm128 (R1-proven config; R8 ledger showed gemm256 QKV+FF1 = +30us)
    dim3 g1024(8, 64);
    gemm128<1><<<g1024, 256, 0, stream>>>(xb, wqT, b_q, qb, 8192, 1024, 1024);
    gemm128<2><<<g1024, 256, 0, stream>>>(xb, wkT, b_k, kb, 8192, 1024, 1024);
    gemm128<3><<<g1024, 256, 0, stream>>>(xb, wvT, b_v, vb, 8192, 1024, 1024);

    attn_kernel<<<2048, 256, 0, stream>>>(qb, kb, vb, gate, mask, ctx);

    gemm128<0><<<g1024, 256, 0, stream>>>(ctx, woT, b_o, attn_out, 8192, 1024, 1024);
    ln_kernel<<<8192, 256, 0, stream>>>(x, attn_out, g1, be1, x1f, x1b);
    // FF1 stays on gemm256 (512 blocks = 2/CU; isolates FF1-on-gemm256 share)
    gemm256<6><<<512, 512, 0, stream>>>(x1b, w1T, b1, hbuf, 8192, 4096, 1024);
    gemm128<0><<<g1024, 256, 0, stream>>>(hbuf, w2T, b2, attn_out, 8192, 1024, 4096);
    ln_kernel<<<8192, 256, 0, stream>>>(x1f, attn_out, g2, be2, (float*)d_out, nullptr);
}

// Round 13
// 648.832 us; speedup vs baseline: 1.0596x; 1.0596x over previous
//
#include <hip/hip_runtime.h>
#include <hip/hip_bf16.h>
#include <cstdint>

// ---------------------------------------------------------------------------
// EncoderLayer fused pipeline for MI355X (gfx950)
// B=4 S=2048 D=1024 H=16 DK=64 DFF=4096   M = B*S = 8192
// ---------------------------------------------------------------------------

typedef __bf16 bf16x8 __attribute__((ext_vector_type(8)));
typedef float  f32x4  __attribute__((ext_vector_type(4)));

__device__ __forceinline__ uint16_t f2bf_bits(float f) {
    __hip_bfloat16 h = __float2bfloat16(f);
    return __builtin_bit_cast(uint16_t, h);
}

// raw v_exp_f32: D = 2^S0, single VALU op (exp2f libm adds range-fixup code;
// __expf adds a v_mul by log2e — both measured slower in-loop, R8/R10).
__device__ __forceinline__ float fast_exp2(float x) {
    float r;
    asm("v_exp_f32 %0, %1" : "=v"(r) : "v"(x));
    return r;
}

// async global->LDS, 16B per lane; lds base must be wave-uniform
#define GLOAD16(ldsb, gp) __builtin_amdgcn_global_load_lds( \
    (const __attribute__((address_space(1))) void*)(gp),    \
    (__attribute__((address_space(3))) void*)(ldsb), 16, 0, 0)

// Q pre-scale: DK^-0.5 * log2(e); softmax runs in exp2 domain.
#define QSCALE_LOG2E 0.18033688011112f

// ---------------------------------------------------------------------------
// cast f32 -> bf16 (vectorized)
__global__ __launch_bounds__(256) void cast_bf16_kernel(
    const float* __restrict__ in, __hip_bfloat16* __restrict__ out, size_t n4)
{
    size_t i = (size_t)blockIdx.x * blockDim.x + threadIdx.x;
    if (i >= n4) return;
    float4 v = ((const float4*)in)[i];
    ushort4 o;
    o.x = f2bf_bits(v.x); o.y = f2bf_bits(v.y);
    o.z = f2bf_bits(v.z); o.w = f2bf_bits(v.w);
    ((ushort4*)out)[i] = o;
}

// ---------------------------------------------------------------------------
// transpose + cast: in [K][N] f32 -> out [N][K] bf16. grid (N/32, K/32), block (32,8)
__global__ __launch_bounds__(256) void transpose_cast_kernel(
    const float* __restrict__ in, __hip_bfloat16* __restrict__ out, int K, int N)
{
    __shared__ float t[32][33];
    int n0 = blockIdx.x * 32, k0 = blockIdx.y * 32;
    int tx = threadIdx.x, ty = threadIdx.y;
#pragma unroll
    for (int i = 0; i < 4; ++i)
        t[ty + i * 8][tx] = in[(size_t)(k0 + ty + i * 8) * N + n0 + tx];
    __syncthreads();
#pragma unroll
    for (int i = 0; i < 4; ++i)
        out[(size_t)(n0 + ty + i * 8) * K + k0 + tx] = __float2bfloat16(t[tx][ty + i * 8]);
}

// ---------------------------------------------------------------------------
// gate = sigmoid(x @ w_g + b_g)   x:[8192][1024] f32, w_g:[1024][16], gate:[8192][16]
__global__ __launch_bounds__(256) void gate_kernel(
    const float* __restrict__ x, const float* __restrict__ wg,
    const float* __restrict__ bg, float* __restrict__ gate)
{
    int tid = threadIdx.x, lane = tid & 63, wid = tid >> 6;
    int row = blockIdx.x * 4 + wid;
    const float* xr = x + (size_t)row * 1024;
    float acc[16];
#pragma unroll
    for (int hh = 0; hh < 16; ++hh) acc[hh] = 0.0f;
    for (int k = lane; k < 1024; k += 64) {
        float xv = xr[k];
        const float* wr = wg + (size_t)k * 16;
#pragma unroll
        for (int hh = 0; hh < 16; ++hh) acc[hh] = fmaf(xv, wr[hh], acc[hh]);
    }
#pragma unroll
    for (int hh = 0; hh < 16; ++hh) {
#pragma unroll
        for (int d = 1; d < 64; d <<= 1) acc[hh] += __shfl_xor(acc[hh], d);
    }
    if (lane < 16) {
        float v = 0.0f;
#pragma unroll
        for (int hh = 0; hh < 16; ++hh)
            if (lane == hh) v = acc[hh] + bg[hh];
        gate[(size_t)row * 16 + lane] = 1.0f / (1.0f + __expf(-v));
    }
}

// ---------------------------------------------------------------------------
// LayerNorm(a + b) -> outf (f32) and optionally outb (bf16). One block per row.
__global__ __launch_bounds__(256) void ln_kernel(
    const float* __restrict__ A, const float* __restrict__ Bx,
    const float* __restrict__ g, const float* __restrict__ beta,
    float* __restrict__ outf, __hip_bfloat16* __restrict__ outb)
{
    int row = blockIdx.x, tid = threadIdx.x;
    const float4* a4 = (const float4*)(A  + (size_t)row * 1024);
    const float4* b4 = (const float4*)(Bx + (size_t)row * 1024);
    float4 va = a4[tid], vb = b4[tid];
    float x0 = va.x + vb.x, x1 = va.y + vb.y, x2 = va.z + vb.z, x3 = va.w + vb.w;
    float s  = x0 + x1 + x2 + x3;
    float sq = x0 * x0 + x1 * x1 + x2 * x2 + x3 * x3;
#pragma unroll
    for (int d = 1; d < 64; d <<= 1) { s += __shfl_xor(s, d); sq += __shfl_xor(sq, d); }
    __shared__ float ss[4], ssq[4];
    int wid = tid >> 6, lane = tid & 63;
    if (lane == 0) { ss[wid] = s; ssq[wid] = sq; }
    __syncthreads();
    s  = ss[0] + ss[1] + ss[2] + ss[3];
    sq = ssq[0] + ssq[1] + ssq[2] + ssq[3];
    float mean = s * (1.0f / 1024.0f);
    float var  = sq * (1.0f / 1024.0f) - mean * mean;
    float rstd = rsqrtf(var + 1e-5f);
    float4 gv = ((const float4*)g)[tid], bv = ((const float4*)beta)[tid];
    float y0 = (x0 - mean) * rstd * gv.x + bv.x;
    float y1 = (x1 - mean) * rstd * gv.y + bv.y;
    float y2 = (x2 - mean) * rstd * gv.z + bv.z;
    float y3 = (x3 - mean) * rstd * gv.w + bv.w;
    float4 o; o.x = y0; o.y = y1; o.z = y2; o.w = y3;
    ((float4*)(outf + (size_t)row * 1024))[tid] = o;
    if (outb) {
        ushort4 ob;
        ob.x = f2bf_bits(y0); ob.y = f2bf_bits(y1);
        ob.z = f2bf_bits(y2); ob.w = f2bf_bits(y3);
        ((ushort4*)(outb + (size_t)row * 1024))[tid] = ob;
    }
}

// ---------------------------------------------------------------------------
// GEMM 128x128 (m97 structure): C = A[M][K] @ BT[N][K]^T + bias.
//  EPI 0: f32 [M][N]
//  EPI 1: q  bf16 [B,H,S,DK], scaled by DK^-0.5*log2e (exp2-domain softmax)
//  EPI 2: k  bf16 [B,H,S,DK]
//  EPI 3: v  bf16 [B,H,DK,S]  (transposed)
//  EPI 4: gelu -> bf16 [M][N]
template<int EPI>
__global__ __launch_bounds__(256, 2) void gemm128(
    const __hip_bfloat16* __restrict__ A,
    const __hip_bfloat16* __restrict__ BT,
    const float* __restrict__ bias,
    void* __restrict__ Cout, int M, int N, int K)
{
    __shared__ __align__(16) __hip_bfloat16 As[128 * 64];
    __shared__ __align__(16) __hip_bfloat16 Bs[128 * 64];
    const int tid = threadIdx.x, lane = tid & 63, wid = tid >> 6;
    const int bx = blockIdx.x, by = blockIdx.y;
    const int wr = wid >> 1, wc = wid & 1;

    f32x4 acc[4][4];
#pragma unroll
    for (int i = 0; i < 4; ++i)
#pragma unroll
        for (int j = 0; j < 4; ++j) acc[i][j] = (f32x4){0.f, 0.f, 0.f, 0.f};

    const char* Abase = (const char*)A  + (size_t)(by * 128) * K * 2;
    const char* Bbase = (const char*)BT + (size_t)(bx * 128) * K * 2;
    char* AsB = (char*)As; char* BsB = (char*)Bs;
    const int laneRow = lane >> 3;            // 0..7
    const int laneCol = (lane & 7) * 16;      // byte col in 128B row

    for (int ks = 0; ks < K; ks += 64) {
#pragma unroll
        for (int j = 0; j < 4; ++j) {
            int r = j * 32 + wid * 8 + laneRow;
            size_t goff = (size_t)r * K * 2 + (size_t)ks * 2 + laneCol;
            GLOAD16(AsB + j * 4096 + wid * 1024, Abase + goff);
            GLOAD16(BsB + j * 4096 + wid * 1024, Bbase + goff);
        }
        __syncthreads();
#pragma unroll
        for (int kk = 0; kk < 2; ++kk) {
            const int kob = (kk * 32 + (lane >> 4) * 8) * 2;  // byte offset in k
            bf16x8 a[4], b[4];
#pragma unroll
            for (int mt = 0; mt < 4; ++mt)
                a[mt] = *(const bf16x8*)(AsB + (wr * 64 + mt * 16 + (lane & 15)) * 128 + kob);
#pragma unroll
            for (int nt = 0; nt < 4; ++nt)
                b[nt] = *(const bf16x8*)(BsB + (wc * 64 + nt * 16 + (lane & 15)) * 128 + kob);
#pragma unroll
            for (int mt = 0; mt < 4; ++mt)
#pragma unroll
                for (int nt = 0; nt < 4; ++nt)
                    acc[mt][nt] = __builtin_amdgcn_mfma_f32_16x16x32_bf16(
                        a[mt], b[nt], acc[mt][nt], 0, 0, 0);
        }
        __syncthreads();
    }

    const int m0 = by * 128 + wr * 64;
    const int n0 = bx * 128 + wc * 64;
#pragma unroll
    for (int mt = 0; mt < 4; ++mt) {
#pragma unroll
        for (int nt = 0; nt < 4; ++nt) {
            int n = n0 + nt * 16 + (lane & 15);
            float bv = bias[n];
#pragma unroll
            for (int j = 0; j < 4; ++j) {
                int m = m0 + mt * 16 + (lane >> 4) * 4 + j;
                float v = acc[mt][nt][j] + bv;
                if constexpr (EPI == 0) {
                    ((float*)Cout)[(size_t)m * N + n] = v;
                } else if constexpr (EPI == 1) {
                    int b = m >> 11, s = m & 2047, h = n >> 6, dk = n & 63;
                    ((__hip_bfloat16*)Cout)[((((size_t)b * 16 + h) * 2048 + s) << 6) + dk] =
                        __float2bfloat16(v * QSCALE_LOG2E);
                } else if constexpr (EPI == 2) {
                    int b = m >> 11, s = m & 2047, h = n >> 6, dk = n & 63;
                    ((__hip_bfloat16*)Cout)[((((size_t)b * 16 + h) * 2048 + s) << 6) + dk] =
                        __float2bfloat16(v);
                } else if constexpr (EPI == 3) {
                    int b = m >> 11, s = m & 2047, h = n >> 6, dk = n & 63;
                    ((__hip_bfloat16*)Cout)[(((size_t)b * 16 + h) * 64 + dk) * 2048 + s] =
                        __float2bfloat16(v);
                } else if constexpr (EPI == 4) {
                    float ge = 0.5f * v * (1.0f + erff(v * 0.70710678118654752f));
                    ((__hip_bfloat16*)Cout)[(size_t)m * N + n] = __float2bfloat16(ge);
                }
            }
        }
    }
}

// ---------------------------------------------------------------------------
// Flash attention. Q:[BH][S][64] bf16 (pre-scaled by DK^-0.5*log2e), K, Vt.
// Softmax in exp2 domain via raw v_exp_f32 (1 op; exp2f libm was +5 ops, R10).
// Defer-max (THR=11 bits), l-reduce deferred to epilogue. K/V LDS swizzled,
// XCD-swizzled grid (conflicts=0, FETCH 25MB).
__global__ __launch_bounds__(256, 2) void attn_kernel(
    const __hip_bfloat16* __restrict__ Q,
    const __hip_bfloat16* __restrict__ Kg,
    const __hip_bfloat16* __restrict__ Vt,
    const float* __restrict__ gate,
    const int* __restrict__ mask,
    __hip_bfloat16* __restrict__ ctx)
{
    __shared__ __align__(16) __hip_bfloat16 Ks[64 * 64];
    __shared__ __align__(16) __hip_bfloat16 Vs[64 * 64];
    __shared__ __align__(16) __hip_bfloat16 Ps[4][16 * 64];
    const int tid = threadIdx.x, lane = tid & 63, wid = tid >> 6;

    // XCD swizzle: 2048 blocks, 8 XCDs, 256 blocks/XCD. nwg%8==0 -> bijective.
    int lin = blockIdx.x;
    int nl  = (lin & 7) * 256 + (lin >> 3);
    const int bh = nl >> 5, qt = nl & 31;
    const int b = bh >> 4, h = bh & 15;
    const int q0 = qt * 64 + wid * 16;

    // Q fragments in registers (A-operand: row = lane&15, k contiguous)
    bf16x8 aq[2];
    const __hip_bfloat16* Qbase = Q + ((size_t)bh * 2048 + q0) * 64;
#pragma unroll
    for (int kk = 0; kk < 2; ++kk)
        aq[kk] = *(const bf16x8*)(Qbase + (lane & 15) * 64 + kk * 32 + (lane >> 4) * 8);

    f32x4 octx[4];
#pragma unroll
    for (int dt = 0; dt < 4; ++dt) octx[dt] = (f32x4){0.f, 0.f, 0.f, 0.f};
    float l_part[4] = {0.f, 0.f, 0.f, 0.f};
    float m_cur = 0.0f;                 // wave-uniform deferred max (log2 units)

    const char* Kbase = (const char*)(Kg + (size_t)bh * 2048 * 64);
    const char* Vbase = (const char*)(Vt + (size_t)bh * 64 * 2048);
    char* KsB = (char*)Ks; char* VsB = (char*)Vs;
    char* PsB = (char*)&Ps[wid][0];

    const int srow = (lane >> 3);             // 0..7 row within wave's slab
    const int schunk = lane & 7;              // 16B chunk within 128B row

    for (int kv0 = 0; kv0 < 2048; kv0 += 64) {
#pragma unroll
        for (int j = 0; j < 2; ++j) {
            int off = j * 4096 + wid * 1024;
            int row = j * 32 + wid * 8 + srow;                 // kv row / dk row
            int sc  = (schunk ^ (row & 7)) * 16;               // pre-swizzled source chunk
            GLOAD16(KsB + off, Kbase + (size_t)(kv0 + row) * 128 + sc);
            GLOAD16(VsB + off, Vbase + (size_t)row * 4096 + (size_t)kv0 * 2 + sc);
        }
        // hoist mask loads (used after QK^T; latency hides under staging+MFMA)
        float madd[4];
#pragma unroll
        for (int ct = 0; ct < 4; ++ct) {
            int kvi = kv0 + ct * 16 + (lane & 15);
            madd[ct] = (mask[b * 2048 + kvi] == 0) ? -1e9f : 0.0f;
        }
        __syncthreads();

        // QK^T: scores[q 16][kv 64] per wave (log2 domain)
        f32x4 sfr[4];
#pragma unroll
        for (int ct = 0; ct < 4; ++ct) sfr[ct] = (f32x4){0.f, 0.f, 0.f, 0.f};
        __builtin_amdgcn_s_setprio(1);
#pragma unroll
        for (int kk = 0; kk < 2; ++kk) {
            const int kob = (kk * 32 + (lane >> 4) * 8) * 2;
#pragma unroll
            for (int ct = 0; ct < 4; ++ct) {
                int krow = ct * 16 + (lane & 15);
                bf16x8 bk = *(const bf16x8*)(KsB + ((krow * 128 + kob) ^ ((krow & 7) << 4)));
                sfr[ct] = __builtin_amdgcn_mfma_f32_16x16x32_bf16(aq[kk], bk, sfr[ct], 0, 0, 0);
            }
        }
        __builtin_amdgcn_s_setprio(0);
#pragma unroll
        for (int ct = 0; ct < 4; ++ct) {
#pragma unroll
            for (int r = 0; r < 4; ++r) sfr[ct][r] += madd[ct];
        }

        // lane-local max of this lane's 16 score elements (no cross-lane)
        float mlane = sfr[0][0];
#pragma unroll
        for (int ct = 0; ct < 4; ++ct)
#pragma unroll
            for (int r = 0; r < 4; ++r) mlane = fmaxf(mlane, sfr[ct][r]);

        if (kv0 == 0) {
            // one-time init: m_cur = wave max
            float wm = mlane;
#pragma unroll
            for (int d = 1; d < 64; d <<= 1) wm = fmaxf(wm, __shfl_xor(wm, d));
            m_cur = wm;
        } else if (!__all(mlane <= m_cur + 11.0f)) {
            // rare slow path: raise m_cur, rescale state (uniform factor)
            float wm = mlane;
#pragma unroll
            for (int d = 1; d < 64; d <<= 1) wm = fmaxf(wm, __shfl_xor(wm, d));
            wm = fmaxf(wm, m_cur);
            float c = fast_exp2(m_cur - wm);
            m_cur = wm;
#pragma unroll
            for (int dt = 0; dt < 4; ++dt)
#pragma unroll
                for (int r = 0; r < 4; ++r) octx[dt][r] *= c;
#pragma unroll
            for (int r = 0; r < 4; ++r) l_part[r] *= c;
        }

        // P = 2^(s - m_cur) (bounded by 2^11), accumulate per-lane l, store P
#pragma unroll
        for (int ct = 0; ct < 4; ++ct) {
#pragma unroll
            for (int r = 0; r < 4; ++r) {
                float p = fast_exp2(sfr[ct][r] - m_cur);
                l_part[r] += p;
                int qr = (lane >> 4) * 4 + r;
                int byteoff = (qr * 128 + (ct * 16 + (lane & 15)) * 2) ^ ((qr & 7) << 4);
                *(__hip_bfloat16*)(PsB + byteoff) = __float2bfloat16(p);
            }
        }
        // PV: ctx[q 16][dk 64] += P @ V
        __builtin_amdgcn_s_setprio(1);
#pragma unroll
        for (int kk = 0; kk < 2; ++kk) {
            const int kb = kk * 32 + (lane >> 4) * 8;
            int pbyte = ((lane & 15) * 128 + kb * 2) ^ (((lane & 15) & 7) << 4);
            bf16x8 ap = *(const bf16x8*)(PsB + pbyte);
#pragma unroll
            for (int dt = 0; dt < 4; ++dt) {
                int vrow = dt * 16 + (lane & 15);
                bf16x8 bvv = *(const bf16x8*)(VsB + ((vrow * 128 + kb * 2) ^ ((vrow & 7) << 4)));
                octx[dt] = __builtin_amdgcn_mfma_f32_16x16x32_bf16(ap, bvv, octx[dt], 0, 0, 0);
            }
        }
        __builtin_amdgcn_s_setprio(0);
        __syncthreads();
    }

    // deferred cross-lane l reduction: sum over the 16 lanes sharing lane>>4
#pragma unroll
    for (int r = 0; r < 4; ++r) {
        float s = l_part[r];
        s += __shfl_xor(s, 1); s += __shfl_xor(s, 2);
        s += __shfl_xor(s, 4); s += __shfl_xor(s, 8);
        l_part[r] = s;
    }

    // epilogue: ctx * gate / l  -> bf16 [M][1024]
#pragma unroll
    for (int r = 0; r < 4; ++r) {
        int qg = q0 + (lane >> 4) * 4 + r;
        size_t rowm = (size_t)b * 2048 + qg;
        float gv = gate[rowm * 16 + h];
        float inv = gv / l_part[r];
#pragma unroll
        for (int dt = 0; dt < 4; ++dt)
            ctx[rowm * 1024 + h * 64 + dt * 16 + (lane & 15)] =
                __float2bfloat16(octx[dt][r] * inv);
    }
}

// ---------------------------------------------------------------------------
extern "C" void kernel_launch(void* const* d_in, const int* in_sizes, int n_in,
                              void* d_out, int out_size, void* d_ws, size_t ws_size,
                              hipStream_t stream)
{
    const float* x    = (const float*)d_in[0];
    const float* w_q  = (const float*)d_in[1];
    const float* b_q  = (const float*)d_in[2];
    const float* w_k  = (const float*)d_in[3];
    const float* b_k  = (const float*)d_in[4];
    const float* w_v  = (const float*)d_in[5];
    const float* b_v  = (const float*)d_in[6];
    const float* w_o  = (const float*)d_in[7];
    const float* b_o  = (const float*)d_in[8];
    const float* w_g  = (const float*)d_in[9];
    const float* b_g  = (const float*)d_in[10];
    const float* w1   = (const float*)d_in[11];
    const float* b1   = (const float*)d_in[12];
    const float* w2   = (const float*)d_in[13];
    const float* b2   = (const float*)d_in[14];
    const float* g1   = (const float*)d_in[15];
    const float* be1  = (const float*)d_in[16];
    const float* g2   = (const float*)d_in[17];
    const float* be2  = (const float*)d_in[18];
    const int*   mask = (const int*)d_in[19];

    char* ws = (char*)d_ws;
    size_t off = 0;
    auto alloc = [&](size_t bytes) -> char* {
        char* p = ws + off; off += (bytes + 255) & ~(size_t)255; return p;
    };

    // Region A: xb | q | k | v  (later reused as FF hidden buffer, 64MB)
    char* regionA = alloc(67108864);
    __hip_bfloat16* xb   = (__hip_bfloat16*)regionA;
    __hip_bfloat16* qb   = (__hip_bfloat16*)(regionA + 16777216);
    __hip_bfloat16* kb   = (__hip_bfloat16*)(regionA + 33554432);
    __hip_bfloat16* vb   = (__hip_bfloat16*)(regionA + 50331648);
    __hip_bfloat16* hbuf = (__hip_bfloat16*)regionA;   // alias (FF1 out / FF2 in)

    __hip_bfloat16* wqT = (__hip_bfloat16*)alloc(2097152);
    __hip_bfloat16* wkT = (__hip_bfloat16*)alloc(2097152);
    __hip_bfloat16* wvT = (__hip_bfloat16*)alloc(2097152);
    __hip_bfloat16* woT = (__hip_bfloat16*)alloc(2097152);
    __hip_bfloat16* w1T = (__hip_bfloat16*)alloc(8388608);
    __hip_bfloat16* w2T = (__hip_bfloat16*)alloc(8388608);
    float* gate       = (float*)alloc(524288);
    __hip_bfloat16* ctx = (__hip_bfloat16*)alloc(16777216);
    float* attn_out   = (float*)alloc(33554432);   // reused as ff2 out
    float* x1f        = (float*)alloc(33554432);
    __hip_bfloat16* x1b = (__hip_bfloat16*)alloc(16777216);

    dim3 tb(32, 8);
    cast_bf16_kernel<<<8192, 256, 0, stream>>>(x, xb, 2097152);
    transpose_cast_kernel<<<dim3(32, 32),  tb, 0, stream>>>(w_q, wqT, 1024, 1024);
    transpose_cast_kernel<<<dim3(32, 32),  tb, 0, stream>>>(w_k, wkT, 1024, 1024);
    transpose_cast_kernel<<<dim3(32, 32),  tb, 0, stream>>>(w_v, wvT, 1024, 1024);
    transpose_cast_kernel<<<dim3(32, 32),  tb, 0, stream>>>(w_o, woT, 1024, 1024);
    transpose_cast_kernel<<<dim3(128, 32), tb, 0, stream>>>(w1, w1T, 1024, 4096);
    transpose_cast_kernel<<<dim3(32, 128), tb, 0, stream>>>(w2, w2T, 4096, 1024);
    gate_kernel<<<2048, 256, 0, stream>>>(x, w_g, b_g, gate);

    // All GEMMs on gemm128 (R10 A/B: gemm256 ≡ gemm128 for QKV; FF1-on-gemm256
    // was the +29us regression vs R1 -> full revert to the R1-proven GEMM set).
    dim3 g1024(8, 64);
    gemm128<1><<<g1024, 256, 0, stream>>>(xb, wqT, b_q, qb, 8192, 1024, 1024);
    gemm128<2><<<g1024, 256, 0, stream>>>(xb, wkT, b_k, kb, 8192, 1024, 1024);
    gemm128<3><<<g1024, 256, 0, stream>>>(xb, wvT, b_v, vb, 8192, 1024, 1024);

    attn_kernel<<<2048, 256, 0, stream>>>(qb, kb, vb, gate, mask, ctx);

    gemm128<0><<<g1024, 256, 0, stream>>>(ctx, woT, b_o, attn_out, 8192, 1024, 1024);
    ln_kernel<<<8192, 256, 0, stream>>>(x, attn_out, g1, be1, x1f, x1b);
    gemm128<4><<<dim3(32, 64), 256, 0, stream>>>(x1b, w1T, b1, hbuf, 8192, 4096, 1024);
    gemm128<0><<<g1024, 256, 0, stream>>>(hbuf, w2T, b2, attn_out, 8192, 1024, 4096);
    ln_kernel<<<8192, 256, 0, stream>>>(x1f, attn_out, g2, be2, (float*)d_out, nullptr);
}